// Round 9
// baseline (227.015 us; speedup 1.0000x reference)
//
#include <hip/hip_runtime.h>

#define NB 4
#define QLEN 2048
#define KLEN 2048
#define QDIM 512
#define EMBED 1024
#define HEADS 16
#define HD 64

typedef __bf16 bf16x8 __attribute__((ext_vector_type(8)));
typedef float f32x2 __attribute__((ext_vector_type(2)));
typedef float f32x4 __attribute__((ext_vector_type(4)));
typedef float f32x16 __attribute__((ext_vector_type(16)));

#define CLOG 0.18033688011112042f   // 0.125 * log2(e), folded into Wq

// guaranteed-cheap exp2
__device__ __forceinline__ float fexp2(float x) {
#if __has_builtin(__builtin_amdgcn_exp2f)
    return __builtin_amdgcn_exp2f(x);
#else
    float r;
    asm("v_exp_f32 %0, %1\n\ts_nop 1" : "=v"(r) : "v"(x));
    return r;
#endif
}

#if __has_builtin(__builtin_amdgcn_sched_barrier)
#define SCHED_FENCE() __builtin_amdgcn_sched_barrier(0)
#else
#define SCHED_FENCE()
#endif

// async global->LDS 16B: dest = wave-uniform base + lane*16
__device__ __forceinline__ void dma16(const void* g, void* l) {
    __builtin_amdgcn_global_load_lds(
        (const __attribute__((address_space(1))) void*)g,
        (__attribute__((address_space(3))) void*)l, 16, 0, 0);
}

// ---------------------------------------------------------------------------
// prep: fused bf16 casts (q,k,v) + W transposes + per-n mask prefix-sum
// (compaction index pidx, counts, and zero-fill of K/V pad rows).
// 1D grid of 4612 blocks x 256.
// ---------------------------------------------------------------------------
__global__ __launch_bounds__(256) void prep(const float* __restrict__ q,
                                            const float* __restrict__ k,
                                            const float* __restrict__ v,
                                            const float* __restrict__ Wq,
                                            const float* __restrict__ Wk,
                                            const float* __restrict__ Wv,
                                            const int* __restrict__ mask,
                                            __bf16* __restrict__ qd,
                                            __bf16* __restrict__ kd,
                                            __bf16* __restrict__ vd,
                                            __bf16* __restrict__ WtQ,
                                            __bf16* __restrict__ WtK,
                                            __bf16* __restrict__ WtV,
                                            int* __restrict__ pidx,
                                            int* __restrict__ cntg,
                                            __bf16* __restrict__ kbf,
                                            __bf16* __restrict__ vtbf) {
    __shared__ float tile[32][33];
    __shared__ int part[256];
    int b = blockIdx.x, tid = threadIdx.x;
    if (b >= 4608) {
        // mask prefix-sum for batch n: positions of valid columns + pad zero-fill
        int n = b - 4608;
        const int* mp = mask + n * KLEN + tid * 8;
        int4 ma = *(const int4*)&mp[0];
        int4 mb = *(const int4*)&mp[4];
        int m[8] = { ma.x, ma.y, ma.z, ma.w, mb.x, mb.y, mb.z, mb.w };
        int c = 0;
#pragma unroll
        for (int j = 0; j < 8; j++) c += (m[j] != 0);
        part[tid] = c;
        __syncthreads();
        for (int off = 1; off < 256; off <<= 1) {
            int vv = (tid >= off) ? part[tid - off] : 0;
            __syncthreads();
            part[tid] += vv;
            __syncthreads();
        }
        int pos = part[tid] - c;           // exclusive prefix
        int* pw = pidx + n * KLEN + tid * 8;
#pragma unroll
        for (int j = 0; j < 8; j++) {
            pw[j] = m[j] ? pos : -1;
            pos += (m[j] != 0);
        }
        int cnt = part[255];
        if (tid == 0) cntg[n] = cnt;
        int tiles = (cnt + 63) >> 6, pe = tiles << 6, np = pe - cnt;
        // zero-fill pads: K rows [cnt,pe) all heads; vT cols [cnt,pe) all (h,d)
        for (int h = 0; h < HEADS; h++) {
            __bf16* kb0 = kbf + (((size_t)(n * HEADS + h)) * KLEN + cnt) * HD;
            __bf16* vb0 = vtbf + ((size_t)(n * HEADS + h)) * HD * KLEN;
            for (int i = tid; i < np * HD; i += 256) {
                int r = i >> 6, d = i & 63;
                kb0[r * HD + d] = (__bf16)0.f;
                vb0[(size_t)d * KLEN + cnt + r] = (__bf16)0.f;
            }
        }
    } else if (b < 3072) {
        const float* src; __bf16* dst; int cb;
        if (b < 2048)      { src = q; dst = qd; cb = b; }
        else if (b < 2560) { src = k; dst = kd; cb = b - 2048; }
        else               { src = v; dst = vd; cb = b - 2560; }
        int i = (cb * 256 + tid) * 8;
        float4 a0 = *(const float4*)&src[i];
        float4 a1 = *(const float4*)&src[i + 4];
        bf16x8 o;
        o[0] = (__bf16)a0.x; o[1] = (__bf16)a0.y; o[2] = (__bf16)a0.z; o[3] = (__bf16)a0.w;
        o[4] = (__bf16)a1.x; o[5] = (__bf16)a1.y; o[6] = (__bf16)a1.z; o[7] = (__bf16)a1.w;
        *(bf16x8*)&dst[i] = o;
    } else {
        int tb = b - 3072;
        int which = tb >> 9, r = tb & 511;
        const float* src = (which == 0) ? Wq : (which == 1) ? Wk : Wv;
        __bf16* dst = (which == 0) ? WtQ : (which == 1) ? WtK : WtV;
        float scale = (which == 0) ? CLOG : 1.0f;
        int e0 = (r & 31) * 32, c0 = (r >> 5) * 32;
        int tx = tid & 31, ty = tid >> 5;  // 32 x 8
        for (int i = 0; i < 4; i++)
            tile[ty + 8 * i][tx] = src[(c0 + ty + 8 * i) * EMBED + e0 + tx];
        __syncthreads();
        for (int i = 0; i < 4; i++)
            dst[(e0 + ty + 8 * i) * QDIM + c0 + tx] = (__bf16)(tile[tx][ty + 8 * i] * scale);
    }
}

// ---------------------------------------------------------------------------
// 128x128-tile GEMM body, double-buffered DMA staging, BK=32, 2x2 wave grid
// (round-5 verified proj structure).
// ---------------------------------------------------------------------------
__device__ __forceinline__ void gemm_compute(const __bf16* As, const __bf16* Bs,
                                             int wr, int wc, int r16, int qq,
                                             f32x4 (&acc)[4][4]) {
    bf16x8 af[4], bq[4];
#pragma unroll
    for (int i = 0; i < 4; i++)
        af[i] = *(const bf16x8*)&As[(wr * 64 + i * 16 + r16) * 32 + qq * 8];
#pragma unroll
    for (int j = 0; j < 4; j++)
        bq[j] = *(const bf16x8*)&Bs[(wc * 64 + j * 16 + r16) * 32 + qq * 8];
#pragma unroll
    for (int i = 0; i < 4; i++)
#pragma unroll
        for (int j = 0; j < 4; j++)
            acc[i][j] = __builtin_amdgcn_mfma_f32_16x16x32_bf16(af[i], bq[j], acc[i][j], 0, 0, 0);
}

__device__ __forceinline__ void gemm128(const __bf16* __restrict__ A,
                                        const __bf16* __restrict__ Bt,
                                        __bf16* As0, __bf16* As1,
                                        __bf16* Bs0, __bf16* Bs1,
                                        int row0, int col0, f32x4 (&acc)[4][4]) {
    int tid = threadIdx.x, wave = tid >> 6, lane = tid & 63;
    int r16 = lane & 15, qq = lane >> 4;
    int wr = wave >> 1, wc = wave & 1;
    const __bf16* agp1 = A + (size_t)(row0 + (tid >> 2)) * QDIM + (tid & 3) * 8;
    const __bf16* agp2 = A + (size_t)(row0 + 64 + (tid >> 2)) * QDIM + (tid & 3) * 8;
    const __bf16* bgp1 = Bt + (size_t)(col0 + (tid >> 2)) * QDIM + (tid & 3) * 8;
    const __bf16* bgp2 = Bt + (size_t)(col0 + 64 + (tid >> 2)) * QDIM + (tid & 3) * 8;
    __bf16 *a0a = &As0[wave * 512], *a0b = &As0[2048 + wave * 512];
    __bf16 *a1a = &As1[wave * 512], *a1b = &As1[2048 + wave * 512];
    __bf16 *b0a = &Bs0[wave * 512], *b0b = &Bs0[2048 + wave * 512];
    __bf16 *b1a = &Bs1[wave * 512], *b1b = &Bs1[2048 + wave * 512];

    // prologue: tile 0 -> buf0
    dma16(agp1, a0a); dma16(agp2, a0b);
    dma16(bgp1, b0a); dma16(bgp2, b0b);
    agp1 += 32; agp2 += 32; bgp1 += 32; bgp2 += 32;
    __syncthreads();

    for (int t = 0; t < 16; t += 2) {
        // prefetch tile t+1 -> buf1 (t+1 <= 15 always)
        dma16(agp1, a1a); dma16(agp2, a1b);
        dma16(bgp1, b1a); dma16(bgp2, b1b);
        agp1 += 32; agp2 += 32; bgp1 += 32; bgp2 += 32;
        SCHED_FENCE();
        gemm_compute(As0, Bs0, wr, wc, r16, qq, acc);
        __syncthreads();
        if (t + 2 < 16) {
            dma16(agp1, a0a); dma16(agp2, a0b);
            dma16(bgp1, b0a); dma16(bgp2, b0b);
            agp1 += 32; agp2 += 32; bgp1 += 32; bgp2 += 32;
        }
        SCHED_FENCE();
        gemm_compute(As1, Bs1, wr, wc, r16, qq, acc);
        __syncthreads();
    }
}

// ---------------------------------------------------------------------------
// fused projections: bid<512 -> q ; <640 -> k ; else -> vT
// k/vT are written COMPACTED per batch n (only mask-valid k positions, at
// their prefix-sum position). Stores were already scalar 2B, so the row
// scatter costs nothing structural.
// ---------------------------------------------------------------------------
__global__ __launch_bounds__(256) void proj_all(const __bf16* __restrict__ qin,
                                                const __bf16* __restrict__ kin,
                                                const __bf16* __restrict__ vin,
                                                const __bf16* __restrict__ wtq,
                                                const __bf16* __restrict__ wtk,
                                                const __bf16* __restrict__ wtv,
                                                const int* __restrict__ pidx,
                                                __bf16* __restrict__ qout,
                                                __bf16* __restrict__ kout,
                                                __bf16* __restrict__ vtout) {
    __shared__ __align__(16) __bf16 As[2][128 * 32];
    __shared__ __align__(16) __bf16 Bs[2][128 * 32];
    int bid = blockIdx.x;
    const __bf16 *A, *Bt;
    int mode, b;
    if (bid < 512)      { A = qin; Bt = wtq; mode = 0; b = bid; }
    else if (bid < 640) { A = kin; Bt = wtk; mode = 1; b = bid - 512; }
    else                { A = wtv; Bt = vin; mode = 2; b = bid - 640; }
    int row0, col0;
    if (mode == 2) { row0 = (b >> 4) * 128; col0 = (b & 15) * 128; }   // 8 x 16
    else           { row0 = (b >> 3) * 128; col0 = (b & 7) * 128; }
    f32x4 acc[4][4] = {};
    gemm128(A, Bt, As[0], As[1], Bs[0], Bs[1], row0, col0, acc);
    int lane = threadIdx.x & 63, wave = threadIdx.x >> 6;
    int r16 = lane & 15, qq = lane >> 4;
    int wr = wave >> 1, wc = wave & 1;
#pragma unroll
    for (int i = 0; i < 4; i++)
#pragma unroll
        for (int j = 0; j < 4; j++)
#pragma unroll
            for (int rr = 0; rr < 4; rr++) {
                int grow = row0 + wr * 64 + i * 16 + qq * 4 + rr;
                int gcol = col0 + wc * 64 + j * 16 + r16;
                __bf16 v = (__bf16)acc[i][j][rr];
                if (mode == 0) {
                    int hh = gcol >> 6, d = gcol & 63;
                    int n = grow >> 11, qr = grow & 2047;
                    qout[((size_t)(n * HEADS + hh) * QLEN + qr) * HD + d] = v;
                } else if (mode == 1) {
                    int hh = gcol >> 6, d = gcol & 63;
#pragma unroll
                    for (int nn = 0; nn < NB; nn++) {
                        int p = pidx[nn * KLEN + grow];
                        if (p >= 0)
                            kout[((size_t)(nn * HEADS + hh) * KLEN + p) * HD + d] = v;
                    }
                } else {
                    // grow = h*64+d (embed), gcol = k -> vT[n][h][d][pos]
#pragma unroll
                    for (int nn = 0; nn < NB; nn++) {
                        int p = pidx[nn * KLEN + gcol];
                        if (p >= 0)
                            vtout[((size_t)nn * EMBED + grow) * KLEN + p] = v;
                    }
                }
            }
}

// ---------------------------------------------------------------------------
// attention tile compute (round-5 core, mask path deleted: compaction means
// every staged column is valid; C-init = 0).
// ---------------------------------------------------------------------------
__device__ __forceinline__ void attn_tile(const __bf16* ksb, const __bf16* vsb,
                                          const bf16x8 (&qfrag)[4],
                                          int col, int h,
                                          f32x16& o0, f32x16& o1, f32x2& rsl) {
    bf16x8 pfrag[4];
#pragma unroll
    for (int kt2 = 0; kt2 < 2; kt2++) {
        int R = kt2 * 32 + col;
        f32x16 s = {};
        __builtin_amdgcn_s_setprio(1);
#pragma unroll
        for (int c = 0; c < 4; c++) {
            int cc = (2 * c + h) ^ (R & 7);
            bf16x8 kf = *(const bf16x8*)&ksb[(R * 8 + cc) * 8];
            s = __builtin_amdgcn_mfma_f32_32x32x16_bf16(kf, qfrag[c], s, 0, 0, 0);
        }
        __builtin_amdgcn_s_setprio(0);
#pragma unroll
        for (int G = 0; G < 4; G++) {
            int ci = 2 * kt2 + (G >> 1), e0 = (G & 1) * 4;
#pragma unroll
            for (int rr = 0; rr < 4; rr += 2) {
                float p0 = fexp2(s[4 * G + rr]);
                float p1 = fexp2(s[4 * G + rr + 1]);
                f32x2 pp; pp[0] = p0; pp[1] = p1;
                rsl += pp;
                pfrag[ci][e0 + rr] = (__bf16)p0;
                pfrag[ci][e0 + rr + 1] = (__bf16)p1;
            }
        }
    }
    __builtin_amdgcn_s_setprio(1);
#pragma unroll
    for (int c = 0; c < 4; c++) {
        int cc = (2 * c + h) ^ (col & 7);
        bf16x8 v0 = *(const bf16x8*)&vsb[(col * 8 + cc) * 8];
        bf16x8 v1 = *(const bf16x8*)&vsb[((32 + col) * 8 + cc) * 8];
        o0 = __builtin_amdgcn_mfma_f32_32x32x16_bf16(v0, pfrag[c], o0, 0, 0, 0);
        o1 = __builtin_amdgcn_mfma_f32_32x32x16_bf16(v1, pfrag[c], o1, 0, 0, 0);
    }
    __builtin_amdgcn_s_setprio(0);
}

// ---------------------------------------------------------------------------
// fused flash attention v12: round-5 structure (512-thread blocks, 8 waves,
// 256 q-rows, 2 blocks/CU) over COMPACTED K/V: ~cnt/2048 of the tiles,
// no mask anywhere. Pads: K=0 -> P=1, V=0 -> denominator -= npad (exact).
// grid = (QLEN/256, HEADS, N), block 512.
// ---------------------------------------------------------------------------
__global__ __launch_bounds__(512, 4) void attn_kernel(const __bf16* __restrict__ qb,
                                                      const __bf16* __restrict__ kb,
                                                      const __bf16* __restrict__ vtb,
                                                      const int* __restrict__ cntg,
                                                      float* __restrict__ out) {
    __shared__ __align__(16) __bf16 ks[2][4096];
    __shared__ __align__(16) __bf16 vs[2][4096];

    int tid = threadIdx.x, wave = tid >> 6, lane = tid & 63;
    int col = lane & 31, h = lane >> 5;
    int q0 = blockIdx.x * 256, hh = blockIdx.y, n = blockIdx.z;
    int cnt = cntg[n];
    int tiles = (cnt + 63) >> 6;
    int npad = (tiles << 6) - cnt;
    const __bf16* qg = qb + ((size_t)(n * HEADS + hh) * QLEN + q0 + wave * 32 + col) * HD;
    const __bf16* kg = kb + (size_t)(n * HEADS + hh) * KLEN * HD;
    const __bf16* vg = vtb + (size_t)(n * HEADS + hh) * HD * KLEN;

    // Q^T B-frags straight from global
    bf16x8 qfrag[4];
#pragma unroll
    for (int c = 0; c < 4; c++) qfrag[c] = *(const bf16x8*)&qg[c * 16 + h * 8];

    // DMA slot assignment (phi on k rows, XOR chunk swizzle); tid 0..511 spans
    // the full 64-row tile: R1 = tid>>3, one dma16 per array per tile.
    int R1 = tid >> 3, c1 = (tid & 7) ^ (R1 & 7);
    int g1 = (R1 & 0x33) | ((R1 & 4) << 1) | ((R1 & 8) >> 1);
    const __bf16* kgp1 = kg + g1 * HD + c1 * 8;
    const __bf16* vgp1 = vg + (size_t)R1 * KLEN + c1 * 8;

    // prologue: DMA tile 0 -> buf0
    dma16(kgp1, &ks[0][wave * 512]); dma16(vgp1, &vs[0][wave * 512]);
    kgp1 += 64 * HD; vgp1 += 64;
    __syncthreads();

    f32x16 o0 = {}, o1 = {};
    f32x2 rsl = {};

    for (int t = 0; t < tiles; t++) {
        int pc = t & 1, pn = pc ^ 1;
        if (t + 1 < tiles) {
            dma16(kgp1, &ks[pn][wave * 512]); dma16(vgp1, &vs[pn][wave * 512]);
            kgp1 += 64 * HD; vgp1 += 64;
        }
        SCHED_FENCE();
        attn_tile(ks[pc], vs[pc], qfrag, col, h, o0, o1, rsl);
        __syncthreads();
    }

    // epilogue: lane owns q-col q0+wave*32+col; subtract pad contribution
    float rs = rsl[0] + rsl[1];
    rs += __shfl_xor(rs, 32);
    rs -= (float)npad;
    float inv = 1.0f / rs;
    float* op = out + ((size_t)n * QLEN + q0 + wave * 32 + col) * EMBED + hh * HD;
#pragma unroll
    for (int G = 0; G < 4; G++) {
        float4 t0, t1;
        t0.x = o0[4 * G + 0] * inv; t0.y = o0[4 * G + 1] * inv;
        t0.z = o0[4 * G + 2] * inv; t0.w = o0[4 * G + 3] * inv;
        t1.x = o1[4 * G + 0] * inv; t1.y = o1[4 * G + 1] * inv;
        t1.z = o1[4 * G + 2] * inv; t1.w = o1[4 * G + 3] * inv;
        *(float4*)&op[8 * G + 4 * h] = t0;
        *(float4*)&op[32 + 8 * G + 4 * h] = t1;
    }
}

// ---------------------------------------------------------------------------
extern "C" void kernel_launch(void* const* d_in, const int* in_sizes, int n_in,
                              void* d_out, int out_size, void* d_ws, size_t ws_size,
                              hipStream_t stream) {
    const float* queries = (const float*)d_in[0];
    const float* keys    = (const float*)d_in[1];
    const float* values  = (const float*)d_in[2];
    const int*   mask    = (const int*)d_in[3];
    const float* Wq      = (const float*)d_in[4];
    const float* Wk      = (const float*)d_in[5];
    const float* Wv      = (const float*)d_in[6];
    float* out = (float*)d_out;

    const size_t MiB = 1048576;
    char* ws = (char*)d_ws;
    __bf16* qbf   = (__bf16*)(ws);             // 16 MiB  q   [N][H][Q][64] (pre-scaled)
    __bf16* kbf   = (__bf16*)(ws + 16 * MiB);  // 16 MiB  k   [N][H][K][64] compacted
    __bf16* vtbf  = (__bf16*)(ws + 32 * MiB);  // 16 MiB  vT  [N][H][64][K] compacted
    __bf16* wtq   = (__bf16*)(ws + 48 * MiB);  //  1 MiB
    __bf16* wtk   = (__bf16*)(ws + 49 * MiB);
    __bf16* wtv   = (__bf16*)(ws + 50 * MiB);
    __bf16* qin   = (__bf16*)(ws + 51 * MiB);  //  8 MiB
    __bf16* kin   = (__bf16*)(ws + 59 * MiB);  //  2 MiB
    __bf16* vin   = (__bf16*)(ws + 61 * MiB);  //  2 MiB
    int*    pidx  = (int*)(ws + 63 * MiB);     // 32 KiB compaction index
    int*    cntg  = (int*)(ws + 63 * MiB + 65536);  // 16 B valid counts

    prep<<<4612, 256, 0, stream>>>(queries, keys, values, Wq, Wk, Wv, mask,
                                   qin, kin, vin, wtq, wtk, wtv,
                                   pidx, cntg, kbf, vtbf);
    proj_all<<<768, 256, 0, stream>>>(qin, kin, vin, wtq, wtk, wtv, pidx,
                                      qbf, kbf, vtbf);
    attn_kernel<<<dim3(QLEN / 256, HEADS, NB), 512, 0, stream>>>(qbf, kbf, vtbf, cntg, out);
}

// Round 10
// 169.989 us; speedup vs baseline: 1.3355x; 1.3355x over previous
//
#include <hip/hip_runtime.h>

#define NB 4
#define QLEN 2048
#define KLEN 2048
#define QDIM 512
#define EMBED 1024
#define HEADS 16
#define HD 64

typedef __bf16 bf16x8 __attribute__((ext_vector_type(8)));
typedef float f32x2 __attribute__((ext_vector_type(2)));
typedef float f32x4 __attribute__((ext_vector_type(4)));
typedef float f32x16 __attribute__((ext_vector_type(16)));

#define CLOG 0.18033688011112042f   // 0.125 * log2(e), folded into Wq

// guaranteed-cheap exp2
__device__ __forceinline__ float fexp2(float x) {
#if __has_builtin(__builtin_amdgcn_exp2f)
    return __builtin_amdgcn_exp2f(x);
#else
    float r;
    asm("v_exp_f32 %0, %1\n\ts_nop 1" : "=v"(r) : "v"(x));
    return r;
#endif
}

#if __has_builtin(__builtin_amdgcn_sched_barrier)
#define SCHED_FENCE() __builtin_amdgcn_sched_barrier(0)
#else
#define SCHED_FENCE()
#endif

// async global->LDS 16B: dest = wave-uniform base + lane*16
__device__ __forceinline__ void dma16(const void* g, void* l) {
    __builtin_amdgcn_global_load_lds(
        (const __attribute__((address_space(1))) void*)g,
        (__attribute__((address_space(3))) void*)l, 16, 0, 0);
}

// ---------------------------------------------------------------------------
// prep: fused bf16 casts (q,k,v) + W transposes + per-n mask prefix-sum
// + PARALLEL pad zero-fill (64 (n,h) blocks, was 4 serial blocks -> ~50us tail).
// 1D grid of 4676 blocks x 256.
//   b <  3072 : bf16 casts
//   b <  4608 : W transposes
//   b <  4612 : per-n mask prefix scan -> pidx, cntg
//   b >= 4612 : per-(n,h) K/V pad zero-fill (cnt recomputed locally: no
//               cross-block dependency)
// ---------------------------------------------------------------------------
__global__ __launch_bounds__(256) void prep(const float* __restrict__ q,
                                            const float* __restrict__ k,
                                            const float* __restrict__ v,
                                            const float* __restrict__ Wq,
                                            const float* __restrict__ Wk,
                                            const float* __restrict__ Wv,
                                            const int* __restrict__ mask,
                                            __bf16* __restrict__ qd,
                                            __bf16* __restrict__ kd,
                                            __bf16* __restrict__ vd,
                                            __bf16* __restrict__ WtQ,
                                            __bf16* __restrict__ WtK,
                                            __bf16* __restrict__ WtV,
                                            int* __restrict__ pidx,
                                            int* __restrict__ cntg,
                                            __bf16* __restrict__ kbf,
                                            __bf16* __restrict__ vtbf) {
    __shared__ float tile[32][33];
    __shared__ int part[256];
    int b = blockIdx.x, tid = threadIdx.x;
    if (b >= 4612) {
        // parallel pad zero-fill for (n,h)
        int t2 = b - 4612, n = t2 >> 4, h = t2 & 15;
        const int* mp = mask + n * KLEN + tid * 8;
        int4 ma = *(const int4*)&mp[0];
        int4 mb = *(const int4*)&mp[4];
        int c = (ma.x != 0) + (ma.y != 0) + (ma.z != 0) + (ma.w != 0)
              + (mb.x != 0) + (mb.y != 0) + (mb.z != 0) + (mb.w != 0);
        part[tid] = c;
        __syncthreads();
        for (int off = 128; off > 0; off >>= 1) {
            if (tid < off) part[tid] += part[tid + off];
            __syncthreads();
        }
        int cnt = part[0];
        int tiles = (cnt + 63) >> 6, pe = tiles << 6, np = pe - cnt;
        __bf16* kb0 = kbf + (((size_t)(n * HEADS + h)) * KLEN + cnt) * HD;
        __bf16* vb0 = vtbf + ((size_t)(n * HEADS + h)) * HD * KLEN;
        for (int i = tid; i < np * HD; i += 256) {
            int r = i >> 6, d = i & 63;
            kb0[r * HD + d] = (__bf16)0.f;               // coalesced rows
        }
        for (int d = 0; d < HD; d++)
            if (tid < np) vb0[(size_t)d * KLEN + cnt + tid] = (__bf16)0.f;
    } else if (b >= 4608) {
        // mask prefix-sum for batch n: positions of valid columns
        int n = b - 4608;
        const int* mp = mask + n * KLEN + tid * 8;
        int4 ma = *(const int4*)&mp[0];
        int4 mb = *(const int4*)&mp[4];
        int m[8] = { ma.x, ma.y, ma.z, ma.w, mb.x, mb.y, mb.z, mb.w };
        int c = 0;
#pragma unroll
        for (int j = 0; j < 8; j++) c += (m[j] != 0);
        part[tid] = c;
        __syncthreads();
        for (int off = 1; off < 256; off <<= 1) {
            int vv = (tid >= off) ? part[tid - off] : 0;
            __syncthreads();
            part[tid] += vv;
            __syncthreads();
        }
        int pos = part[tid] - c;           // exclusive prefix
        int* pw = pidx + n * KLEN + tid * 8;
#pragma unroll
        for (int j = 0; j < 8; j++) {
            pw[j] = m[j] ? pos : -1;
            pos += (m[j] != 0);
        }
        if (tid == 0) cntg[n] = part[255];
    } else if (b < 3072) {
        const float* src; __bf16* dst; int cb;
        if (b < 2048)      { src = q; dst = qd; cb = b; }
        else if (b < 2560) { src = k; dst = kd; cb = b - 2048; }
        else               { src = v; dst = vd; cb = b - 2560; }
        int i = (cb * 256 + tid) * 8;
        float4 a0 = *(const float4*)&src[i];
        float4 a1 = *(const float4*)&src[i + 4];
        bf16x8 o;
        o[0] = (__bf16)a0.x; o[1] = (__bf16)a0.y; o[2] = (__bf16)a0.z; o[3] = (__bf16)a0.w;
        o[4] = (__bf16)a1.x; o[5] = (__bf16)a1.y; o[6] = (__bf16)a1.z; o[7] = (__bf16)a1.w;
        *(bf16x8*)&dst[i] = o;
    } else {
        int tb = b - 3072;
        int which = tb >> 9, r = tb & 511;
        const float* src = (which == 0) ? Wq : (which == 1) ? Wk : Wv;
        __bf16* dst = (which == 0) ? WtQ : (which == 1) ? WtK : WtV;
        float scale = (which == 0) ? CLOG : 1.0f;
        int e0 = (r & 31) * 32, c0 = (r >> 5) * 32;
        int tx = tid & 31, ty = tid >> 5;  // 32 x 8
        for (int i = 0; i < 4; i++)
            tile[ty + 8 * i][tx] = src[(c0 + ty + 8 * i) * EMBED + e0 + tx];
        __syncthreads();
        for (int i = 0; i < 4; i++)
            dst[(e0 + ty + 8 * i) * QDIM + c0 + tx] = (__bf16)(tile[tx][ty + 8 * i] * scale);
    }
}

// ---------------------------------------------------------------------------
// 128x128-tile GEMM body, double-buffered DMA staging, BK=32, 2x2 wave grid
// (round-5 verified proj structure).
// ---------------------------------------------------------------------------
__device__ __forceinline__ void gemm_compute(const __bf16* As, const __bf16* Bs,
                                             int wr, int wc, int r16, int qq,
                                             f32x4 (&acc)[4][4]) {
    bf16x8 af[4], bq[4];
#pragma unroll
    for (int i = 0; i < 4; i++)
        af[i] = *(const bf16x8*)&As[(wr * 64 + i * 16 + r16) * 32 + qq * 8];
#pragma unroll
    for (int j = 0; j < 4; j++)
        bq[j] = *(const bf16x8*)&Bs[(wc * 64 + j * 16 + r16) * 32 + qq * 8];
#pragma unroll
    for (int i = 0; i < 4; i++)
#pragma unroll
        for (int j = 0; j < 4; j++)
            acc[i][j] = __builtin_amdgcn_mfma_f32_16x16x32_bf16(af[i], bq[j], acc[i][j], 0, 0, 0);
}

__device__ __forceinline__ void gemm128(const __bf16* __restrict__ A,
                                        const __bf16* __restrict__ Bt,
                                        __bf16* As0, __bf16* As1,
                                        __bf16* Bs0, __bf16* Bs1,
                                        int row0, int col0, f32x4 (&acc)[4][4]) {
    int tid = threadIdx.x, wave = tid >> 6, lane = tid & 63;
    int r16 = lane & 15, qq = lane >> 4;
    int wr = wave >> 1, wc = wave & 1;
    const __bf16* agp1 = A + (size_t)(row0 + (tid >> 2)) * QDIM + (tid & 3) * 8;
    const __bf16* agp2 = A + (size_t)(row0 + 64 + (tid >> 2)) * QDIM + (tid & 3) * 8;
    const __bf16* bgp1 = Bt + (size_t)(col0 + (tid >> 2)) * QDIM + (tid & 3) * 8;
    const __bf16* bgp2 = Bt + (size_t)(col0 + 64 + (tid >> 2)) * QDIM + (tid & 3) * 8;
    __bf16 *a0a = &As0[wave * 512], *a0b = &As0[2048 + wave * 512];
    __bf16 *a1a = &As1[wave * 512], *a1b = &As1[2048 + wave * 512];
    __bf16 *b0a = &Bs0[wave * 512], *b0b = &Bs0[2048 + wave * 512];
    __bf16 *b1a = &Bs1[wave * 512], *b1b = &Bs1[2048 + wave * 512];

    // prologue: tile 0 -> buf0
    dma16(agp1, a0a); dma16(agp2, a0b);
    dma16(bgp1, b0a); dma16(bgp2, b0b);
    agp1 += 32; agp2 += 32; bgp1 += 32; bgp2 += 32;
    __syncthreads();

    for (int t = 0; t < 16; t += 2) {
        // prefetch tile t+1 -> buf1 (t+1 <= 15 always)
        dma16(agp1, a1a); dma16(agp2, a1b);
        dma16(bgp1, b1a); dma16(bgp2, b1b);
        agp1 += 32; agp2 += 32; bgp1 += 32; bgp2 += 32;
        SCHED_FENCE();
        gemm_compute(As0, Bs0, wr, wc, r16, qq, acc);
        __syncthreads();
        if (t + 2 < 16) {
            dma16(agp1, a0a); dma16(agp2, a0b);
            dma16(bgp1, b0a); dma16(bgp2, b0b);
            agp1 += 32; agp2 += 32; bgp1 += 32; bgp2 += 32;
        }
        SCHED_FENCE();
        gemm_compute(As1, Bs1, wr, wc, r16, qq, acc);
        __syncthreads();
    }
}

// ---------------------------------------------------------------------------
// fused projections: bid<512 -> q ; <640 -> k ; else -> vT
// k/vT are written COMPACTED per batch n (prefix-sum position via pidx).
// Epilogue split per mode with pidx hoisted (int4 for mode-1 rows, scalar
// hoist for mode-2 cols) -- fewer dependent scalar loads in the store loop.
// ---------------------------------------------------------------------------
__global__ __launch_bounds__(256) void proj_all(const __bf16* __restrict__ qin,
                                                const __bf16* __restrict__ kin,
                                                const __bf16* __restrict__ vin,
                                                const __bf16* __restrict__ wtq,
                                                const __bf16* __restrict__ wtk,
                                                const __bf16* __restrict__ wtv,
                                                const int* __restrict__ pidx,
                                                __bf16* __restrict__ qout,
                                                __bf16* __restrict__ kout,
                                                __bf16* __restrict__ vtout) {
    __shared__ __align__(16) __bf16 As[2][128 * 32];
    __shared__ __align__(16) __bf16 Bs[2][128 * 32];
    int bid = blockIdx.x;
    const __bf16 *A, *Bt;
    int mode, b;
    if (bid < 512)      { A = qin; Bt = wtq; mode = 0; b = bid; }
    else if (bid < 640) { A = kin; Bt = wtk; mode = 1; b = bid - 512; }
    else                { A = wtv; Bt = vin; mode = 2; b = bid - 640; }
    int row0, col0;
    if (mode == 2) { row0 = (b >> 4) * 128; col0 = (b & 15) * 128; }   // 8 x 16
    else           { row0 = (b >> 3) * 128; col0 = (b & 7) * 128; }
    f32x4 acc[4][4] = {};
    gemm128(A, Bt, As[0], As[1], Bs[0], Bs[1], row0, col0, acc);
    int lane = threadIdx.x & 63, wave = threadIdx.x >> 6;
    int r16 = lane & 15, qq = lane >> 4;
    int wr = wave >> 1, wc = wave & 1;

    if (mode == 0) {
#pragma unroll
        for (int i = 0; i < 4; i++)
#pragma unroll
            for (int j = 0; j < 4; j++)
#pragma unroll
                for (int rr = 0; rr < 4; rr++) {
                    int grow = row0 + wr * 64 + i * 16 + qq * 4 + rr;
                    int gcol = col0 + wc * 64 + j * 16 + r16;
                    int hh = gcol >> 6, d = gcol & 63;
                    int n = grow >> 11, qr = grow & 2047;
                    qout[((size_t)(n * HEADS + hh) * QLEN + qr) * HD + d] =
                        (__bf16)acc[i][j][rr];
                }
    } else if (mode == 1) {
#pragma unroll
        for (int i = 0; i < 4; i++) {
            int grow0 = row0 + wr * 64 + i * 16 + qq * 4;   // 16B-aligned
            int4 p4[NB];
#pragma unroll
            for (int nn = 0; nn < NB; nn++)
                p4[nn] = *(const int4*)&pidx[nn * KLEN + grow0];
#pragma unroll
            for (int j = 0; j < 4; j++) {
                int gcol = col0 + wc * 64 + j * 16 + r16;
                int hh = gcol >> 6, d = gcol & 63;
#pragma unroll
                for (int rr = 0; rr < 4; rr++) {
                    __bf16 v = (__bf16)acc[i][j][rr];
#pragma unroll
                    for (int nn = 0; nn < NB; nn++) {
                        int p = ((const int*)&p4[nn])[rr];
                        if (p >= 0)
                            kout[((size_t)(nn * HEADS + hh) * KLEN + p) * HD + d] = v;
                    }
                }
            }
        }
    } else {
        int p2[NB][4];
#pragma unroll
        for (int nn = 0; nn < NB; nn++)
#pragma unroll
            for (int j = 0; j < 4; j++)
                p2[nn][j] = pidx[nn * KLEN + col0 + wc * 64 + j * 16 + r16];
#pragma unroll
        for (int i = 0; i < 4; i++)
#pragma unroll
            for (int j = 0; j < 4; j++)
#pragma unroll
                for (int rr = 0; rr < 4; rr++) {
                    int grow = row0 + wr * 64 + i * 16 + qq * 4 + rr;  // h*64+d
                    __bf16 v = (__bf16)acc[i][j][rr];
#pragma unroll
                    for (int nn = 0; nn < NB; nn++) {
                        int p = p2[nn][j];
                        if (p >= 0)
                            vtout[((size_t)nn * EMBED + grow) * KLEN + p] = v;
                    }
                }
    }
}

// ---------------------------------------------------------------------------
// attention tile compute (round-5 core, mask path deleted: compaction means
// every staged column is valid; C-init = 0).
// ---------------------------------------------------------------------------
__device__ __forceinline__ void attn_tile(const __bf16* ksb, const __bf16* vsb,
                                          const bf16x8 (&qfrag)[4],
                                          int col, int h,
                                          f32x16& o0, f32x16& o1, f32x2& rsl) {
    bf16x8 pfrag[4];
#pragma unroll
    for (int kt2 = 0; kt2 < 2; kt2++) {
        int R = kt2 * 32 + col;
        f32x16 s = {};
        __builtin_amdgcn_s_setprio(1);
#pragma unroll
        for (int c = 0; c < 4; c++) {
            int cc = (2 * c + h) ^ (R & 7);
            bf16x8 kf = *(const bf16x8*)&ksb[(R * 8 + cc) * 8];
            s = __builtin_amdgcn_mfma_f32_32x32x16_bf16(kf, qfrag[c], s, 0, 0, 0);
        }
        __builtin_amdgcn_s_setprio(0);
#pragma unroll
        for (int G = 0; G < 4; G++) {
            int ci = 2 * kt2 + (G >> 1), e0 = (G & 1) * 4;
#pragma unroll
            for (int rr = 0; rr < 4; rr += 2) {
                float p0 = fexp2(s[4 * G + rr]);
                float p1 = fexp2(s[4 * G + rr + 1]);
                f32x2 pp; pp[0] = p0; pp[1] = p1;
                rsl += pp;
                pfrag[ci][e0 + rr] = (__bf16)p0;
                pfrag[ci][e0 + rr + 1] = (__bf16)p1;
            }
        }
    }
    __builtin_amdgcn_s_setprio(1);
#pragma unroll
    for (int c = 0; c < 4; c++) {
        int cc = (2 * c + h) ^ (col & 7);
        bf16x8 v0 = *(const bf16x8*)&vsb[(col * 8 + cc) * 8];
        bf16x8 v1 = *(const bf16x8*)&vsb[((32 + col) * 8 + cc) * 8];
        o0 = __builtin_amdgcn_mfma_f32_32x32x16_bf16(v0, pfrag[c], o0, 0, 0, 0);
        o1 = __builtin_amdgcn_mfma_f32_32x32x16_bf16(v1, pfrag[c], o1, 0, 0, 0);
    }
    __builtin_amdgcn_s_setprio(0);
}

// ---------------------------------------------------------------------------
// fused flash attention v12: round-5 structure (512-thread blocks, 8 waves,
// 256 q-rows, 2 blocks/CU) over COMPACTED K/V: ~cnt/2048 of the tiles,
// no mask anywhere. Pads: K=0 -> P=1, V=0 -> denominator -= npad (exact).
// grid = (QLEN/256, HEADS, N), block 512.
// ---------------------------------------------------------------------------
__global__ __launch_bounds__(512, 4) void attn_kernel(const __bf16* __restrict__ qb,
                                                      const __bf16* __restrict__ kb,
                                                      const __bf16* __restrict__ vtb,
                                                      const int* __restrict__ cntg,
                                                      float* __restrict__ out) {
    __shared__ __align__(16) __bf16 ks[2][4096];
    __shared__ __align__(16) __bf16 vs[2][4096];

    int tid = threadIdx.x, wave = tid >> 6, lane = tid & 63;
    int col = lane & 31, h = lane >> 5;
    int q0 = blockIdx.x * 256, hh = blockIdx.y, n = blockIdx.z;
    int cnt = cntg[n];
    int tiles = (cnt + 63) >> 6;
    int npad = (tiles << 6) - cnt;
    const __bf16* qg = qb + ((size_t)(n * HEADS + hh) * QLEN + q0 + wave * 32 + col) * HD;
    const __bf16* kg = kb + (size_t)(n * HEADS + hh) * KLEN * HD;
    const __bf16* vg = vtb + (size_t)(n * HEADS + hh) * HD * KLEN;

    // Q^T B-frags straight from global
    bf16x8 qfrag[4];
#pragma unroll
    for (int c = 0; c < 4; c++) qfrag[c] = *(const bf16x8*)&qg[c * 16 + h * 8];

    // DMA slot assignment (phi on k rows, XOR chunk swizzle); tid 0..511 spans
    // the full 64-row tile: R1 = tid>>3, one dma16 per array per tile.
    int R1 = tid >> 3, c1 = (tid & 7) ^ (R1 & 7);
    int g1 = (R1 & 0x33) | ((R1 & 4) << 1) | ((R1 & 8) >> 1);
    const __bf16* kgp1 = kg + g1 * HD + c1 * 8;
    const __bf16* vgp1 = vg + (size_t)R1 * KLEN + c1 * 8;

    // prologue: DMA tile 0 -> buf0
    dma16(kgp1, &ks[0][wave * 512]); dma16(vgp1, &vs[0][wave * 512]);
    kgp1 += 64 * HD; vgp1 += 64;
    __syncthreads();

    f32x16 o0 = {}, o1 = {};
    f32x2 rsl = {};

    for (int t = 0; t < tiles; t++) {
        int pc = t & 1, pn = pc ^ 1;
        if (t + 1 < tiles) {
            dma16(kgp1, &ks[pn][wave * 512]); dma16(vgp1, &vs[pn][wave * 512]);
            kgp1 += 64 * HD; vgp1 += 64;
        }
        SCHED_FENCE();
        attn_tile(ks[pc], vs[pc], qfrag, col, h, o0, o1, rsl);
        __syncthreads();
    }

    // epilogue: lane owns q-col q0+wave*32+col; subtract pad contribution
    float rs = rsl[0] + rsl[1];
    rs += __shfl_xor(rs, 32);
    rs -= (float)npad;
    float inv = 1.0f / rs;
    float* op = out + ((size_t)n * QLEN + q0 + wave * 32 + col) * EMBED + hh * HD;
#pragma unroll
    for (int G = 0; G < 4; G++) {
        float4 t0, t1;
        t0.x = o0[4 * G + 0] * inv; t0.y = o0[4 * G + 1] * inv;
        t0.z = o0[4 * G + 2] * inv; t0.w = o0[4 * G + 3] * inv;
        t1.x = o1[4 * G + 0] * inv; t1.y = o1[4 * G + 1] * inv;
        t1.z = o1[4 * G + 2] * inv; t1.w = o1[4 * G + 3] * inv;
        *(float4*)&op[8 * G + 4 * h] = t0;
        *(float4*)&op[32 + 8 * G + 4 * h] = t1;
    }
}

// ---------------------------------------------------------------------------
extern "C" void kernel_launch(void* const* d_in, const int* in_sizes, int n_in,
                              void* d_out, int out_size, void* d_ws, size_t ws_size,
                              hipStream_t stream) {
    const float* queries = (const float*)d_in[0];
    const float* keys    = (const float*)d_in[1];
    const float* values  = (const float*)d_in[2];
    const int*   mask    = (const int*)d_in[3];
    const float* Wq      = (const float*)d_in[4];
    const float* Wk      = (const float*)d_in[5];
    const float* Wv      = (const float*)d_in[6];
    float* out = (float*)d_out;

    const size_t MiB = 1048576;
    char* ws = (char*)d_ws;
    __bf16* qbf   = (__bf16*)(ws);             // 16 MiB  q   [N][H][Q][64] (pre-scaled)
    __bf16* kbf   = (__bf16*)(ws + 16 * MiB);  // 16 MiB  k   [N][H][K][64] compacted
    __bf16* vtbf  = (__bf16*)(ws + 32 * MiB);  // 16 MiB  vT  [N][H][64][K] compacted
    __bf16* wtq   = (__bf16*)(ws + 48 * MiB);  //  1 MiB
    __bf16* wtk   = (__bf16*)(ws + 49 * MiB);
    __bf16* wtv   = (__bf16*)(ws + 50 * MiB);
    __bf16* qin   = (__bf16*)(ws + 51 * MiB);  //  8 MiB
    __bf16* kin   = (__bf16*)(ws + 59 * MiB);  //  2 MiB
    __bf16* vin   = (__bf16*)(ws + 61 * MiB);  //  2 MiB
    int*    pidx  = (int*)(ws + 63 * MiB);     // 32 KiB compaction index
    int*    cntg  = (int*)(ws + 63 * MiB + 65536);  // 16 B valid counts

    prep<<<4676, 256, 0, stream>>>(queries, keys, values, Wq, Wk, Wv, mask,
                                   qin, kin, vin, wtq, wtk, wtv,
                                   pidx, cntg, kbf, vtbf);
    proj_all<<<768, 256, 0, stream>>>(qin, kin, vin, wtq, wtk, wtv, pidx,
                                      qbf, kbf, vtbf);
    attn_kernel<<<dim3(QLEN / 256, HEADS, NB), 512, 0, stream>>>(qbf, kbf, vtbf, cntg, out);
}

// Round 11
// 169.876 us; speedup vs baseline: 1.3364x; 1.0007x over previous
//
#include <hip/hip_runtime.h>

#define NB 4
#define QLEN 2048
#define KLEN 2048
#define QDIM 512
#define EMBED 1024
#define HEADS 16
#define HD 64

typedef __bf16 bf16x8 __attribute__((ext_vector_type(8)));
typedef float f32x2 __attribute__((ext_vector_type(2)));
typedef float f32x4 __attribute__((ext_vector_type(4)));
typedef float f32x16 __attribute__((ext_vector_type(16)));

#define CLOG 0.18033688011112042f   // 0.125 * log2(e), folded into Wq

// guaranteed-cheap exp2
__device__ __forceinline__ float fexp2(float x) {
#if __has_builtin(__builtin_amdgcn_exp2f)
    return __builtin_amdgcn_exp2f(x);
#else
    float r;
    asm("v_exp_f32 %0, %1\n\ts_nop 1" : "=v"(r) : "v"(x));
    return r;
#endif
}

#if __has_builtin(__builtin_amdgcn_sched_barrier)
#define SCHED_FENCE() __builtin_amdgcn_sched_barrier(0)
#else
#define SCHED_FENCE()
#endif

// async global->LDS 16B: dest = wave-uniform base + lane*16
__device__ __forceinline__ void dma16(const void* g, void* l) {
    __builtin_amdgcn_global_load_lds(
        (const __attribute__((address_space(1))) void*)g,
        (__attribute__((address_space(3))) void*)l, 16, 0, 0);
}

// ---------------------------------------------------------------------------
// prep: fused bf16 casts (q,k,v) + W transposes + per-n mask prefix-sum
// + parallel pad zero-fill. 1D grid of 4676 blocks x 256. (round-10 verified)
// ---------------------------------------------------------------------------
__global__ __launch_bounds__(256) void prep(const float* __restrict__ q,
                                            const float* __restrict__ k,
                                            const float* __restrict__ v,
                                            const float* __restrict__ Wq,
                                            const float* __restrict__ Wk,
                                            const float* __restrict__ Wv,
                                            const int* __restrict__ mask,
                                            __bf16* __restrict__ qd,
                                            __bf16* __restrict__ kd,
                                            __bf16* __restrict__ vd,
                                            __bf16* __restrict__ WtQ,
                                            __bf16* __restrict__ WtK,
                                            __bf16* __restrict__ WtV,
                                            int* __restrict__ pidx,
                                            int* __restrict__ cntg,
                                            __bf16* __restrict__ kbf,
                                            __bf16* __restrict__ vtbf) {
    __shared__ float tile[32][33];
    __shared__ int part[256];
    int b = blockIdx.x, tid = threadIdx.x;
    if (b >= 4612) {
        // parallel pad zero-fill for (n,h)
        int t2 = b - 4612, n = t2 >> 4, h = t2 & 15;
        const int* mp = mask + n * KLEN + tid * 8;
        int4 ma = *(const int4*)&mp[0];
        int4 mb = *(const int4*)&mp[4];
        int c = (ma.x != 0) + (ma.y != 0) + (ma.z != 0) + (ma.w != 0)
              + (mb.x != 0) + (mb.y != 0) + (mb.z != 0) + (mb.w != 0);
        part[tid] = c;
        __syncthreads();
        for (int off = 128; off > 0; off >>= 1) {
            if (tid < off) part[tid] += part[tid + off];
            __syncthreads();
        }
        int cnt = part[0];
        int tiles = (cnt + 63) >> 6, pe = tiles << 6, np = pe - cnt;
        __bf16* kb0 = kbf + (((size_t)(n * HEADS + h)) * KLEN + cnt) * HD;
        __bf16* vb0 = vtbf + ((size_t)(n * HEADS + h)) * HD * KLEN;
        for (int i = tid; i < np * HD; i += 256) {
            int r = i >> 6, d = i & 63;
            kb0[r * HD + d] = (__bf16)0.f;               // coalesced rows
        }
        for (int d = 0; d < HD; d++)
            if (tid < np) vb0[(size_t)d * KLEN + cnt + tid] = (__bf16)0.f;
    } else if (b >= 4608) {
        // mask prefix-sum for batch n: positions of valid columns
        int n = b - 4608;
        const int* mp = mask + n * KLEN + tid * 8;
        int4 ma = *(const int4*)&mp[0];
        int4 mb = *(const int4*)&mp[4];
        int m[8] = { ma.x, ma.y, ma.z, ma.w, mb.x, mb.y, mb.z, mb.w };
        int c = 0;
#pragma unroll
        for (int j = 0; j < 8; j++) c += (m[j] != 0);
        part[tid] = c;
        __syncthreads();
        for (int off = 1; off < 256; off <<= 1) {
            int vv = (tid >= off) ? part[tid - off] : 0;
            __syncthreads();
            part[tid] += vv;
            __syncthreads();
        }
        int pos = part[tid] - c;           // exclusive prefix
        int* pw = pidx + n * KLEN + tid * 8;
#pragma unroll
        for (int j = 0; j < 8; j++) {
            pw[j] = m[j] ? pos : -1;
            pos += (m[j] != 0);
        }
        if (tid == 0) cntg[n] = part[255];
    } else if (b < 3072) {
        const float* src; __bf16* dst; int cb;
        if (b < 2048)      { src = q; dst = qd; cb = b; }
        else if (b < 2560) { src = k; dst = kd; cb = b - 2048; }
        else               { src = v; dst = vd; cb = b - 2560; }
        int i = (cb * 256 + tid) * 8;
        float4 a0 = *(const float4*)&src[i];
        float4 a1 = *(const float4*)&src[i + 4];
        bf16x8 o;
        o[0] = (__bf16)a0.x; o[1] = (__bf16)a0.y; o[2] = (__bf16)a0.z; o[3] = (__bf16)a0.w;
        o[4] = (__bf16)a1.x; o[5] = (__bf16)a1.y; o[6] = (__bf16)a1.z; o[7] = (__bf16)a1.w;
        *(bf16x8*)&dst[i] = o;
    } else {
        int tb = b - 3072;
        int which = tb >> 9, r = tb & 511;
        const float* src = (which == 0) ? Wq : (which == 1) ? Wk : Wv;
        __bf16* dst = (which == 0) ? WtQ : (which == 1) ? WtK : WtV;
        float scale = (which == 0) ? CLOG : 1.0f;
        int e0 = (r & 31) * 32, c0 = (r >> 5) * 32;
        int tx = tid & 31, ty = tid >> 5;  // 32 x 8
        for (int i = 0; i < 4; i++)
            tile[ty + 8 * i][tx] = src[(c0 + ty + 8 * i) * EMBED + e0 + tx];
        __syncthreads();
        for (int i = 0; i < 4; i++)
            dst[(e0 + ty + 8 * i) * QDIM + c0 + tx] = (__bf16)(tile[tx][ty + 8 * i] * scale);
    }
}

// ---------------------------------------------------------------------------
// 128x128-tile GEMM body, double-buffered DMA staging, BK=32, 2x2 wave grid
// (round-5 verified proj structure).
// ---------------------------------------------------------------------------
__device__ __forceinline__ void gemm_compute(const __bf16* As, const __bf16* Bs,
                                             int wr, int wc, int r16, int qq,
                                             f32x4 (&acc)[4][4]) {
    bf16x8 af[4], bq[4];
#pragma unroll
    for (int i = 0; i < 4; i++)
        af[i] = *(const bf16x8*)&As[(wr * 64 + i * 16 + r16) * 32 + qq * 8];
#pragma unroll
    for (int j = 0; j < 4; j++)
        bq[j] = *(const bf16x8*)&Bs[(wc * 64 + j * 16 + r16) * 32 + qq * 8];
#pragma unroll
    for (int i = 0; i < 4; i++)
#pragma unroll
        for (int j = 0; j < 4; j++)
            acc[i][j] = __builtin_amdgcn_mfma_f32_16x16x32_bf16(af[i], bq[j], acc[i][j], 0, 0, 0);
}

__device__ __forceinline__ void gemm128(const __bf16* __restrict__ A,
                                        const __bf16* __restrict__ Bt,
                                        __bf16* As0, __bf16* As1,
                                        __bf16* Bs0, __bf16* Bs1,
                                        int row0, int col0, f32x4 (&acc)[4][4]) {
    int tid = threadIdx.x, wave = tid >> 6, lane = tid & 63;
    int r16 = lane & 15, qq = lane >> 4;
    int wr = wave >> 1, wc = wave & 1;
    const __bf16* agp1 = A + (size_t)(row0 + (tid >> 2)) * QDIM + (tid & 3) * 8;
    const __bf16* agp2 = A + (size_t)(row0 + 64 + (tid >> 2)) * QDIM + (tid & 3) * 8;
    const __bf16* bgp1 = Bt + (size_t)(col0 + (tid >> 2)) * QDIM + (tid & 3) * 8;
    const __bf16* bgp2 = Bt + (size_t)(col0 + 64 + (tid >> 2)) * QDIM + (tid & 3) * 8;
    __bf16 *a0a = &As0[wave * 512], *a0b = &As0[2048 + wave * 512];
    __bf16 *a1a = &As1[wave * 512], *a1b = &As1[2048 + wave * 512];
    __bf16 *b0a = &Bs0[wave * 512], *b0b = &Bs0[2048 + wave * 512];
    __bf16 *b1a = &Bs1[wave * 512], *b1b = &Bs1[2048 + wave * 512];

    // prologue: tile 0 -> buf0
    dma16(agp1, a0a); dma16(agp2, a0b);
    dma16(bgp1, b0a); dma16(bgp2, b0b);
    agp1 += 32; agp2 += 32; bgp1 += 32; bgp2 += 32;
    __syncthreads();

    for (int t = 0; t < 16; t += 2) {
        // prefetch tile t+1 -> buf1 (t+1 <= 15 always)
        dma16(agp1, a1a); dma16(agp2, a1b);
        dma16(bgp1, b1a); dma16(bgp2, b1b);
        agp1 += 32; agp2 += 32; bgp1 += 32; bgp2 += 32;
        SCHED_FENCE();
        gemm_compute(As0, Bs0, wr, wc, r16, qq, acc);
        __syncthreads();
        if (t + 2 < 16) {
            dma16(agp1, a0a); dma16(agp2, a0b);
            dma16(bgp1, b0a); dma16(bgp2, b0b);
            agp1 += 32; agp2 += 32; bgp1 += 32; bgp2 += 32;
        }
        SCHED_FENCE();
        gemm_compute(As1, Bs1, wr, wc, r16, qq, acc);
        __syncthreads();
    }
}

// ---------------------------------------------------------------------------
// fused projections: bid<512 -> q ; <640 -> k ; else -> vT
// k/vT are written COMPACTED per batch n (prefix-sum position via pidx).
// ---------------------------------------------------------------------------
__global__ __launch_bounds__(256) void proj_all(const __bf16* __restrict__ qin,
                                                const __bf16* __restrict__ kin,
                                                const __bf16* __restrict__ vin,
                                                const __bf16* __restrict__ wtq,
                                                const __bf16* __restrict__ wtk,
                                                const __bf16* __restrict__ wtv,
                                                const int* __restrict__ pidx,
                                                __bf16* __restrict__ qout,
                                                __bf16* __restrict__ kout,
                                                __bf16* __restrict__ vtout) {
    __shared__ __align__(16) __bf16 As[2][128 * 32];
    __shared__ __align__(16) __bf16 Bs[2][128 * 32];
    int bid = blockIdx.x;
    const __bf16 *A, *Bt;
    int mode, b;
    if (bid < 512)      { A = qin; Bt = wtq; mode = 0; b = bid; }
    else if (bid < 640) { A = kin; Bt = wtk; mode = 1; b = bid - 512; }
    else                { A = wtv; Bt = vin; mode = 2; b = bid - 640; }
    int row0, col0;
    if (mode == 2) { row0 = (b >> 4) * 128; col0 = (b & 15) * 128; }   // 8 x 16
    else           { row0 = (b >> 3) * 128; col0 = (b & 7) * 128; }
    f32x4 acc[4][4] = {};
    gemm128(A, Bt, As[0], As[1], Bs[0], Bs[1], row0, col0, acc);
    int lane = threadIdx.x & 63, wave = threadIdx.x >> 6;
    int r16 = lane & 15, qq = lane >> 4;
    int wr = wave >> 1, wc = wave & 1;

    if (mode == 0) {
#pragma unroll
        for (int i = 0; i < 4; i++)
#pragma unroll
            for (int j = 0; j < 4; j++)
#pragma unroll
                for (int rr = 0; rr < 4; rr++) {
                    int grow = row0 + wr * 64 + i * 16 + qq * 4 + rr;
                    int gcol = col0 + wc * 64 + j * 16 + r16;
                    int hh = gcol >> 6, d = gcol & 63;
                    int n = grow >> 11, qr = grow & 2047;
                    qout[((size_t)(n * HEADS + hh) * QLEN + qr) * HD + d] =
                        (__bf16)acc[i][j][rr];
                }
    } else if (mode == 1) {
#pragma unroll
        for (int i = 0; i < 4; i++) {
            int grow0 = row0 + wr * 64 + i * 16 + qq * 4;   // 16B-aligned
            int4 p4[NB];
#pragma unroll
            for (int nn = 0; nn < NB; nn++)
                p4[nn] = *(const int4*)&pidx[nn * KLEN + grow0];
#pragma unroll
            for (int j = 0; j < 4; j++) {
                int gcol = col0 + wc * 64 + j * 16 + r16;
                int hh = gcol >> 6, d = gcol & 63;
#pragma unroll
                for (int rr = 0; rr < 4; rr++) {
                    __bf16 v = (__bf16)acc[i][j][rr];
#pragma unroll
                    for (int nn = 0; nn < NB; nn++) {
                        int p = ((const int*)&p4[nn])[rr];
                        if (p >= 0)
                            kout[((size_t)(nn * HEADS + hh) * KLEN + p) * HD + d] = v;
                    }
                }
            }
        }
    } else {
        int p2[NB][4];
#pragma unroll
        for (int nn = 0; nn < NB; nn++)
#pragma unroll
            for (int j = 0; j < 4; j++)
                p2[nn][j] = pidx[nn * KLEN + col0 + wc * 64 + j * 16 + r16];
#pragma unroll
        for (int i = 0; i < 4; i++)
#pragma unroll
            for (int j = 0; j < 4; j++)
#pragma unroll
                for (int rr = 0; rr < 4; rr++) {
                    int grow = row0 + wr * 64 + i * 16 + qq * 4 + rr;  // h*64+d
                    __bf16 v = (__bf16)acc[i][j][rr];
#pragma unroll
                    for (int nn = 0; nn < NB; nn++) {
                        int p = p2[nn][j];
                        if (p >= 0)
                            vtout[((size_t)nn * EMBED + grow) * KLEN + p] = v;
                    }
                }
    }
}

// ---------------------------------------------------------------------------
// attention tile compute (round-5 core, mask path deleted; C-init = 0).
// ---------------------------------------------------------------------------
__device__ __forceinline__ void attn_tile(const __bf16* ksb, const __bf16* vsb,
                                          const bf16x8 (&qfrag)[4],
                                          int col, int h,
                                          f32x16& o0, f32x16& o1, f32x2& rsl) {
    bf16x8 pfrag[4];
#pragma unroll
    for (int kt2 = 0; kt2 < 2; kt2++) {
        int R = kt2 * 32 + col;
        f32x16 s = {};
        __builtin_amdgcn_s_setprio(1);
#pragma unroll
        for (int c = 0; c < 4; c++) {
            int cc = (2 * c + h) ^ (R & 7);
            bf16x8 kf = *(const bf16x8*)&ksb[(R * 8 + cc) * 8];
            s = __builtin_amdgcn_mfma_f32_32x32x16_bf16(kf, qfrag[c], s, 0, 0, 0);
        }
        __builtin_amdgcn_s_setprio(0);
#pragma unroll
        for (int G = 0; G < 4; G++) {
            int ci = 2 * kt2 + (G >> 1), e0 = (G & 1) * 4;
#pragma unroll
            for (int rr = 0; rr < 4; rr += 2) {
                float p0 = fexp2(s[4 * G + rr]);
                float p1 = fexp2(s[4 * G + rr + 1]);
                f32x2 pp; pp[0] = p0; pp[1] = p1;
                rsl += pp;
                pfrag[ci][e0 + rr] = (__bf16)p0;
                pfrag[ci][e0 + rr + 1] = (__bf16)p1;
            }
        }
    }
    __builtin_amdgcn_s_setprio(1);
#pragma unroll
    for (int c = 0; c < 4; c++) {
        int cc = (2 * c + h) ^ (col & 7);
        bf16x8 v0 = *(const bf16x8*)&vsb[(col * 8 + cc) * 8];
        bf16x8 v1 = *(const bf16x8*)&vsb[((32 + col) * 8 + cc) * 8];
        o0 = __builtin_amdgcn_mfma_f32_32x32x16_bf16(v0, pfrag[c], o0, 0, 0, 0);
        o1 = __builtin_amdgcn_mfma_f32_32x32x16_bf16(v1, pfrag[c], o1, 0, 0, 0);
    }
    __builtin_amdgcn_s_setprio(0);
}

// ---------------------------------------------------------------------------
// fused flash attention v13: round-10 core over compacted K/V, with
// XCD-LOCALITY grid order (T1): 1D grid 512, q-tile index is the SLOW dim so
// the 8 q-blocks sharing one (n,h) K/V slice have ids differing by 64 = 0
// (mod 8 XCDs) -> same XCD -> slice fetched once per XCD (was 8 XCD copies:
// FETCH 76.8 MB vs ideal 33 MB).
// ---------------------------------------------------------------------------
__global__ __launch_bounds__(512, 4) void attn_kernel(const __bf16* __restrict__ qb,
                                                      const __bf16* __restrict__ kb,
                                                      const __bf16* __restrict__ vtb,
                                                      const int* __restrict__ cntg,
                                                      float* __restrict__ out) {
    __shared__ __align__(16) __bf16 ks[2][4096];
    __shared__ __align__(16) __bf16 vs[2][4096];

    int tid = threadIdx.x, wave = tid >> 6, lane = tid & 63;
    int col = lane & 31, h = lane >> 5;
    int bid = blockIdx.x;
    int qx = bid >> 6, r6 = bid & 63, hh = r6 >> 2, n = r6 & 3;
    int q0 = qx * 256;
    int cnt = cntg[n];
    int tiles = (cnt + 63) >> 6;
    int npad = (tiles << 6) - cnt;
    const __bf16* qg = qb + ((size_t)(n * HEADS + hh) * QLEN + q0 + wave * 32 + col) * HD;
    const __bf16* kg = kb + (size_t)(n * HEADS + hh) * KLEN * HD;
    const __bf16* vg = vtb + (size_t)(n * HEADS + hh) * HD * KLEN;

    // Q^T B-frags straight from global
    bf16x8 qfrag[4];
#pragma unroll
    for (int c = 0; c < 4; c++) qfrag[c] = *(const bf16x8*)&qg[c * 16 + h * 8];

    // DMA slot assignment (phi on k rows, XOR chunk swizzle); tid 0..511 spans
    // the full 64-row tile: R1 = tid>>3, one dma16 per array per tile.
    int R1 = tid >> 3, c1 = (tid & 7) ^ (R1 & 7);
    int g1 = (R1 & 0x33) | ((R1 & 4) << 1) | ((R1 & 8) >> 1);
    const __bf16* kgp1 = kg + g1 * HD + c1 * 8;
    const __bf16* vgp1 = vg + (size_t)R1 * KLEN + c1 * 8;

    // prologue: DMA tile 0 -> buf0
    dma16(kgp1, &ks[0][wave * 512]); dma16(vgp1, &vs[0][wave * 512]);
    kgp1 += 64 * HD; vgp1 += 64;
    __syncthreads();

    f32x16 o0 = {}, o1 = {};
    f32x2 rsl = {};

    for (int t = 0; t < tiles; t++) {
        int pc = t & 1, pn = pc ^ 1;
        if (t + 1 < tiles) {
            dma16(kgp1, &ks[pn][wave * 512]); dma16(vgp1, &vs[pn][wave * 512]);
            kgp1 += 64 * HD; vgp1 += 64;
        }
        SCHED_FENCE();
        attn_tile(ks[pc], vs[pc], qfrag, col, h, o0, o1, rsl);
        __syncthreads();
    }

    // epilogue: lane owns q-col q0+wave*32+col; subtract pad contribution
    float rs = rsl[0] + rsl[1];
    rs += __shfl_xor(rs, 32);
    rs -= (float)npad;
    float inv = 1.0f / rs;
    float* op = out + ((size_t)n * QLEN + q0 + wave * 32 + col) * EMBED + hh * HD;
#pragma unroll
    for (int G = 0; G < 4; G++) {
        float4 t0, t1;
        t0.x = o0[4 * G + 0] * inv; t0.y = o0[4 * G + 1] * inv;
        t0.z = o0[4 * G + 2] * inv; t0.w = o0[4 * G + 3] * inv;
        t1.x = o1[4 * G + 0] * inv; t1.y = o1[4 * G + 1] * inv;
        t1.z = o1[4 * G + 2] * inv; t1.w = o1[4 * G + 3] * inv;
        *(float4*)&op[8 * G + 4 * h] = t0;
        *(float4*)&op[32 + 8 * G + 4 * h] = t1;
    }
}

// ---------------------------------------------------------------------------
extern "C" void kernel_launch(void* const* d_in, const int* in_sizes, int n_in,
                              void* d_out, int out_size, void* d_ws, size_t ws_size,
                              hipStream_t stream) {
    const float* queries = (const float*)d_in[0];
    const float* keys    = (const float*)d_in[1];
    const float* values  = (const float*)d_in[2];
    const int*   mask    = (const int*)d_in[3];
    const float* Wq      = (const float*)d_in[4];
    const float* Wk      = (const float*)d_in[5];
    const float* Wv      = (const float*)d_in[6];
    float* out = (float*)d_out;

    const size_t MiB = 1048576;
    char* ws = (char*)d_ws;
    __bf16* qbf   = (__bf16*)(ws);             // 16 MiB  q   [N][H][Q][64] (pre-scaled)
    __bf16* kbf   = (__bf16*)(ws + 16 * MiB);  // 16 MiB  k   [N][H][K][64] compacted
    __bf16* vtbf  = (__bf16*)(ws + 32 * MiB);  // 16 MiB  vT  [N][H][64][K] compacted
    __bf16* wtq   = (__bf16*)(ws + 48 * MiB);  //  1 MiB
    __bf16* wtk   = (__bf16*)(ws + 49 * MiB);
    __bf16* wtv   = (__bf16*)(ws + 50 * MiB);
    __bf16* qin   = (__bf16*)(ws + 51 * MiB);  //  8 MiB
    __bf16* kin   = (__bf16*)(ws + 59 * MiB);  //  2 MiB
    __bf16* vin   = (__bf16*)(ws + 61 * MiB);  //  2 MiB
    int*    pidx  = (int*)(ws + 63 * MiB);     // 32 KiB compaction index
    int*    cntg  = (int*)(ws + 63 * MiB + 65536);  // 16 B valid counts

    prep<<<4676, 256, 0, stream>>>(queries, keys, values, Wq, Wk, Wv, mask,
                                   qin, kin, vin, wtq, wtk, wtv,
                                   pidx, cntg, kbf, vtbf);
    proj_all<<<768, 256, 0, stream>>>(qin, kin, vin, wtq, wtk, wtv, pidx,
                                      qbf, kbf, vtbf);
    attn_kernel<<<512, 512, 0, stream>>>(qbf, kbf, vtbf, cntg, out);
}

// Round 12
// 161.021 us; speedup vs baseline: 1.4098x; 1.0550x over previous
//
#include <hip/hip_runtime.h>

#define NB 4
#define QLEN 2048
#define KLEN 2048
#define QDIM 512
#define EMBED 1024
#define HEADS 16
#define HD 64

typedef __bf16 bf16x8 __attribute__((ext_vector_type(8)));
typedef float f32x2 __attribute__((ext_vector_type(2)));
typedef float f32x4 __attribute__((ext_vector_type(4)));
typedef float f32x16 __attribute__((ext_vector_type(16)));

#define CLOG 0.18033688011112042f   // 0.125 * log2(e), folded into Wq

// guaranteed-cheap exp2
__device__ __forceinline__ float fexp2(float x) {
#if __has_builtin(__builtin_amdgcn_exp2f)
    return __builtin_amdgcn_exp2f(x);
#else
    float r;
    asm("v_exp_f32 %0, %1\n\ts_nop 1" : "=v"(r) : "v"(x));
    return r;
#endif
}

#if __has_builtin(__builtin_amdgcn_sched_barrier)
#define SCHED_FENCE() __builtin_amdgcn_sched_barrier(0)
#else
#define SCHED_FENCE()
#endif

// async global->LDS 16B: dest = wave-uniform base + lane*16
__device__ __forceinline__ void dma16(const void* g, void* l) {
    __builtin_amdgcn_global_load_lds(
        (const __attribute__((address_space(1))) void*)g,
        (__attribute__((address_space(3))) void*)l, 16, 0, 0);
}

// ---------------------------------------------------------------------------
// prep: fused bf16 casts (q,k,v) + W transposes + per-n mask prefix-sum
// (pidx, cidx inverse index, pst per-128-chunk p-offsets) + parallel pad
// zero-fill. 1D grid of 4676 blocks x 256. (round-11 verified + cidx/pst)
// ---------------------------------------------------------------------------
__global__ __launch_bounds__(256) void prep(const float* __restrict__ q,
                                            const float* __restrict__ k,
                                            const float* __restrict__ v,
                                            const float* __restrict__ Wq,
                                            const float* __restrict__ Wk,
                                            const float* __restrict__ Wv,
                                            const int* __restrict__ mask,
                                            __bf16* __restrict__ qd,
                                            __bf16* __restrict__ kd,
                                            __bf16* __restrict__ vd,
                                            __bf16* __restrict__ WtQ,
                                            __bf16* __restrict__ WtK,
                                            __bf16* __restrict__ WtV,
                                            int* __restrict__ pidx,
                                            int* __restrict__ cntg,
                                            __bf16* __restrict__ kbf,
                                            __bf16* __restrict__ vtbf,
                                            int* __restrict__ cidx,
                                            int* __restrict__ pst) {
    __shared__ float tile[32][33];
    __shared__ int part[256];
    int b = blockIdx.x, tid = threadIdx.x;
    if (b >= 4612) {
        // parallel pad zero-fill for (n,h)
        int t2 = b - 4612, n = t2 >> 4, h = t2 & 15;
        const int* mp = mask + n * KLEN + tid * 8;
        int4 ma = *(const int4*)&mp[0];
        int4 mb = *(const int4*)&mp[4];
        int c = (ma.x != 0) + (ma.y != 0) + (ma.z != 0) + (ma.w != 0)
              + (mb.x != 0) + (mb.y != 0) + (mb.z != 0) + (mb.w != 0);
        part[tid] = c;
        __syncthreads();
        for (int off = 128; off > 0; off >>= 1) {
            if (tid < off) part[tid] += part[tid + off];
            __syncthreads();
        }
        int cnt = part[0];
        int tiles = (cnt + 63) >> 6, pe = tiles << 6, np = pe - cnt;
        __bf16* kb0 = kbf + (((size_t)(n * HEADS + h)) * KLEN + cnt) * HD;
        __bf16* vb0 = vtbf + ((size_t)(n * HEADS + h)) * HD * KLEN;
        for (int i = tid; i < np * HD; i += 256) {
            int r = i >> 6, d = i & 63;
            kb0[r * HD + d] = (__bf16)0.f;               // coalesced rows
        }
        for (int d = 0; d < HD; d++)
            if (tid < np) vb0[(size_t)d * KLEN + cnt + tid] = (__bf16)0.f;
    } else if (b >= 4608) {
        // mask prefix-sum for batch n: pidx (dense->compact), cidx (compact->dense),
        // pst[n][17] p-offset at each 128-chunk boundary (+cnt at [16])
        int n = b - 4608;
        const int* mp = mask + n * KLEN + tid * 8;
        int4 ma = *(const int4*)&mp[0];
        int4 mb = *(const int4*)&mp[4];
        int m[8] = { ma.x, ma.y, ma.z, ma.w, mb.x, mb.y, mb.z, mb.w };
        int c = 0;
#pragma unroll
        for (int j = 0; j < 8; j++) c += (m[j] != 0);
        part[tid] = c;
        __syncthreads();
        for (int off = 1; off < 256; off <<= 1) {
            int vv = (tid >= off) ? part[tid - off] : 0;
            __syncthreads();
            part[tid] += vv;
            __syncthreads();
        }
        int pos = part[tid] - c;           // exclusive prefix
        int* pw = pidx + n * KLEN + tid * 8;
        int* cw = cidx + n * KLEN;
#pragma unroll
        for (int j = 0; j < 8; j++) {
            pw[j] = m[j] ? pos : -1;
            if (m[j]) cw[pos] = tid * 8 + j;
            pos += (m[j] != 0);
        }
        if ((tid & 15) == 0) pst[n * 17 + (tid >> 4)] = part[tid] - c;
        if (tid == 255) pst[n * 17 + 16] = part[255];
        if (tid == 0) cntg[n] = part[255];
    } else if (b < 3072) {
        const float* src; __bf16* dst; int cb;
        if (b < 2048)      { src = q; dst = qd; cb = b; }
        else if (b < 2560) { src = k; dst = kd; cb = b - 2048; }
        else               { src = v; dst = vd; cb = b - 2560; }
        int i = (cb * 256 + tid) * 8;
        float4 a0 = *(const float4*)&src[i];
        float4 a1 = *(const float4*)&src[i + 4];
        bf16x8 o;
        o[0] = (__bf16)a0.x; o[1] = (__bf16)a0.y; o[2] = (__bf16)a0.z; o[3] = (__bf16)a0.w;
        o[4] = (__bf16)a1.x; o[5] = (__bf16)a1.y; o[6] = (__bf16)a1.z; o[7] = (__bf16)a1.w;
        *(bf16x8*)&dst[i] = o;
    } else {
        int tb = b - 3072;
        int which = tb >> 9, r = tb & 511;
        const float* src = (which == 0) ? Wq : (which == 1) ? Wk : Wv;
        __bf16* dst = (which == 0) ? WtQ : (which == 1) ? WtK : WtV;
        float scale = (which == 0) ? CLOG : 1.0f;
        int e0 = (r & 31) * 32, c0 = (r >> 5) * 32;
        int tx = tid & 31, ty = tid >> 5;  // 32 x 8
        for (int i = 0; i < 4; i++)
            tile[ty + 8 * i][tx] = src[(c0 + ty + 8 * i) * EMBED + e0 + tx];
        __syncthreads();
        for (int i = 0; i < 4; i++)
            dst[(e0 + ty + 8 * i) * QDIM + c0 + tx] = (__bf16)(tile[tx][ty + 8 * i] * scale);
    }
}

// ---------------------------------------------------------------------------
// 128x128-tile GEMM body, double-buffered DMA staging, BK=32, 2x2 wave grid
// (round-5 verified proj structure).
// ---------------------------------------------------------------------------
__device__ __forceinline__ void gemm_compute(const __bf16* As, const __bf16* Bs,
                                             int wr, int wc, int r16, int qq,
                                             f32x4 (&acc)[4][4]) {
    bf16x8 af[4], bq[4];
#pragma unroll
    for (int i = 0; i < 4; i++)
        af[i] = *(const bf16x8*)&As[(wr * 64 + i * 16 + r16) * 32 + qq * 8];
#pragma unroll
    for (int j = 0; j < 4; j++)
        bq[j] = *(const bf16x8*)&Bs[(wc * 64 + j * 16 + r16) * 32 + qq * 8];
#pragma unroll
    for (int i = 0; i < 4; i++)
#pragma unroll
        for (int j = 0; j < 4; j++)
            acc[i][j] = __builtin_amdgcn_mfma_f32_16x16x32_bf16(af[i], bq[j], acc[i][j], 0, 0, 0);
}

__device__ __forceinline__ void gemm128(const __bf16* __restrict__ A,
                                        const __bf16* __restrict__ Bt,
                                        __bf16* As0, __bf16* As1,
                                        __bf16* Bs0, __bf16* Bs1,
                                        int row0, int col0, f32x4 (&acc)[4][4]) {
    int tid = threadIdx.x, wave = tid >> 6, lane = tid & 63;
    int r16 = lane & 15, qq = lane >> 4;
    int wr = wave >> 1, wc = wave & 1;
    const __bf16* agp1 = A + (size_t)(row0 + (tid >> 2)) * QDIM + (tid & 3) * 8;
    const __bf16* agp2 = A + (size_t)(row0 + 64 + (tid >> 2)) * QDIM + (tid & 3) * 8;
    const __bf16* bgp1 = Bt + (size_t)(col0 + (tid >> 2)) * QDIM + (tid & 3) * 8;
    const __bf16* bgp2 = Bt + (size_t)(col0 + 64 + (tid >> 2)) * QDIM + (tid & 3) * 8;
    __bf16 *a0a = &As0[wave * 512], *a0b = &As0[2048 + wave * 512];
    __bf16 *a1a = &As1[wave * 512], *a1b = &As1[2048 + wave * 512];
    __bf16 *b0a = &Bs0[wave * 512], *b0b = &Bs0[2048 + wave * 512];
    __bf16 *b1a = &Bs1[wave * 512], *b1b = &Bs1[2048 + wave * 512];

    // prologue: tile 0 -> buf0
    dma16(agp1, a0a); dma16(agp2, a0b);
    dma16(bgp1, b0a); dma16(bgp2, b0b);
    agp1 += 32; agp2 += 32; bgp1 += 32; bgp2 += 32;
    __syncthreads();

    for (int t = 0; t < 16; t += 2) {
        // prefetch tile t+1 -> buf1 (t+1 <= 15 always)
        dma16(agp1, a1a); dma16(agp2, a1b);
        dma16(bgp1, b1a); dma16(bgp2, b1b);
        agp1 += 32; agp2 += 32; bgp1 += 32; bgp2 += 32;
        SCHED_FENCE();
        gemm_compute(As0, Bs0, wr, wc, r16, qq, acc);
        __syncthreads();
        if (t + 2 < 16) {
            dma16(agp1, a0a); dma16(agp2, a0b);
            dma16(bgp1, b0a); dma16(bgp2, b0b);
            agp1 += 32; agp2 += 32; bgp1 += 32; bgp2 += 32;
        }
        SCHED_FENCE();
        gemm_compute(As1, Bs1, wr, wc, r16, qq, acc);
        __syncthreads();
    }
}

// ---------------------------------------------------------------------------
// fused projections: bid<128 -> vT (slowest first) ; <256 -> k ; else -> q
// k/vT written COMPACTED per batch n. Mode-2 stores via LDS tile staging +
// cidx gather -> aligned bf16x8 runs (monotone compaction => valid k in a
// 128-dense-range map to consecutive p).
// ---------------------------------------------------------------------------
__global__ __launch_bounds__(256) void proj_all(const __bf16* __restrict__ qin,
                                                const __bf16* __restrict__ kin,
                                                const __bf16* __restrict__ vin,
                                                const __bf16* __restrict__ wtq,
                                                const __bf16* __restrict__ wtk,
                                                const __bf16* __restrict__ wtv,
                                                const int* __restrict__ pidx,
                                                const int* __restrict__ cidx,
                                                const int* __restrict__ pst,
                                                __bf16* __restrict__ qout,
                                                __bf16* __restrict__ kout,
                                                __bf16* __restrict__ vtout) {
    __shared__ __align__(16) __bf16 smem[16384];   // As0|As1|Bs0|Bs1, reused as Ct
    int bid = blockIdx.x;
    const __bf16 *A, *Bt;
    int mode, b, row0, col0;
    if (bid < 128)      { A = wtv; Bt = vin; mode = 2; b = bid;
                          row0 = (b >> 4) * 128; col0 = (b & 15) * 128; }   // 8x16
    else if (bid < 256) { A = kin; Bt = wtk; mode = 1; b = bid - 128;
                          row0 = (b >> 3) * 128; col0 = (b & 7) * 128; }    // 16x8
    else                { A = qin; Bt = wtq; mode = 0; b = bid - 256;
                          row0 = (b >> 3) * 128; col0 = (b & 7) * 128; }    // 64x8
    f32x4 acc[4][4] = {};
    gemm128(A, Bt, smem, smem + 4096, smem + 8192, smem + 12288, row0, col0, acc);
    int tid = threadIdx.x;
    int lane = tid & 63, wave = tid >> 6;
    int r16 = lane & 15, qq = lane >> 4;
    int wr = wave >> 1, wc = wave & 1;

    if (mode == 0) {
#pragma unroll
        for (int i = 0; i < 4; i++)
#pragma unroll
            for (int j = 0; j < 4; j++)
#pragma unroll
                for (int rr = 0; rr < 4; rr++) {
                    int grow = row0 + wr * 64 + i * 16 + qq * 4 + rr;
                    int gcol = col0 + wc * 64 + j * 16 + r16;
                    int hh = gcol >> 6, d = gcol & 63;
                    int n = grow >> 11, qr = grow & 2047;
                    qout[((size_t)(n * HEADS + hh) * QLEN + qr) * HD + d] =
                        (__bf16)acc[i][j][rr];
                }
    } else if (mode == 1) {
#pragma unroll
        for (int i = 0; i < 4; i++) {
            int grow0 = row0 + wr * 64 + i * 16 + qq * 4;   // 16B-aligned
            int4 p4[NB];
#pragma unroll
            for (int nn = 0; nn < NB; nn++)
                p4[nn] = *(const int4*)&pidx[nn * KLEN + grow0];
#pragma unroll
            for (int j = 0; j < 4; j++) {
                int gcol = col0 + wc * 64 + j * 16 + r16;
                int hh = gcol >> 6, d = gcol & 63;
#pragma unroll
                for (int rr = 0; rr < 4; rr++) {
                    __bf16 v = (__bf16)acc[i][j][rr];
#pragma unroll
                    for (int nn = 0; nn < NB; nn++) {
                        int p = ((const int*)&p4[nn])[rr];
                        if (p >= 0)
                            kout[((size_t)(nn * HEADS + hh) * KLEN + p) * HD + d] = v;
                    }
                }
            }
        }
    } else {
        // ---- mode 2: stage tile to LDS, then coalesced compacted writes ----
        __bf16* Ct = smem;                 // [128][128] bf16 = 32KB
        // (gemm128 ends with __syncthreads: safe to overwrite staging bufs)
#pragma unroll
        for (int i = 0; i < 4; i++)
#pragma unroll
            for (int j = 0; j < 4; j++)
#pragma unroll
                for (int rr = 0; rr < 4; rr++) {
                    int row = wr * 64 + i * 16 + qq * 4 + rr;     // e - row0
                    int colx = wc * 64 + j * 16 + r16;            // k - col0
                    Ct[row * 128 + colx] = (__bf16)acc[i][j][rr];
                }
        __syncthreads();
        int ci0 = col0 >> 7;
        for (int nn = 0; nn < NB; nn++) {
            int pstart = pst[nn * 17 + ci0];
            int pend   = pst[nn * 17 + ci0 + 1];
            int cv = pend - pstart;
            if (cv <= 0) continue;
            const int* cix = cidx + nn * KLEN;
            __bf16* vbase = vtout + (size_t)(nn * EMBED + row0) * KLEN;
            int p0a = (pstart + 7) & ~7;       // aligned chunk start
            int p1a = pend & ~7;               // aligned chunk end
            int headEnd = min(p0a, pend);
            int nh = headEnd - pstart;
            if (nh > 0) {
                int r = tid & 7;
                if (r < nh) {
                    int p = pstart + r;
                    int kk = cix[p] - col0;
                    for (int e = tid >> 3; e < 128; e += 32)
                        vbase[(size_t)e * KLEN + p] = Ct[e * 128 + kk];
                }
            }
            if (p1a > p0a) {
                int nch = (p1a - p0a) >> 3;
                for (int ch = tid & 31; ch < nch; ch += 32) {
                    int p = p0a + ch * 8;
                    int4 ca = *(const int4*)&cix[p];
                    int4 cb = *(const int4*)&cix[p + 4];
                    int k0 = ca.x - col0, k1 = ca.y - col0, k2 = ca.z - col0, k3 = ca.w - col0;
                    int k4 = cb.x - col0, k5 = cb.y - col0, k6 = cb.z - col0, k7 = cb.w - col0;
                    for (int e = tid >> 5; e < 128; e += 8) {
                        const __bf16* cr = &Ct[e * 128];
                        bf16x8 o;
                        o[0] = cr[k0]; o[1] = cr[k1]; o[2] = cr[k2]; o[3] = cr[k3];
                        o[4] = cr[k4]; o[5] = cr[k5]; o[6] = cr[k6]; o[7] = cr[k7];
                        *(bf16x8*)&vbase[(size_t)e * KLEN + p] = o;
                    }
                }
            }
            int t0 = max(p1a, headEnd);
            int nt = pend - t0;
            if (nt > 0) {
                int r = tid & 7;
                if (r < nt) {
                    int p = t0 + r;
                    int kk = cix[p] - col0;
                    for (int e = tid >> 3; e < 128; e += 32)
                        vbase[(size_t)e * KLEN + p] = Ct[e * 128 + kk];
                }
            }
        }
    }
}

// ---------------------------------------------------------------------------
// attention tile compute (round-5 core, mask path deleted; C-init = 0).
// ---------------------------------------------------------------------------
__device__ __forceinline__ void attn_tile(const __bf16* ksb, const __bf16* vsb,
                                          const bf16x8 (&qfrag)[4],
                                          int col, int h,
                                          f32x16& o0, f32x16& o1, f32x2& rsl) {
    bf16x8 pfrag[4];
#pragma unroll
    for (int kt2 = 0; kt2 < 2; kt2++) {
        int R = kt2 * 32 + col;
        f32x16 s = {};
        __builtin_amdgcn_s_setprio(1);
#pragma unroll
        for (int c = 0; c < 4; c++) {
            int cc = (2 * c + h) ^ (R & 7);
            bf16x8 kf = *(const bf16x8*)&ksb[(R * 8 + cc) * 8];
            s = __builtin_amdgcn_mfma_f32_32x32x16_bf16(kf, qfrag[c], s, 0, 0, 0);
        }
        __builtin_amdgcn_s_setprio(0);
#pragma unroll
        for (int G = 0; G < 4; G++) {
            int ci = 2 * kt2 + (G >> 1), e0 = (G & 1) * 4;
#pragma unroll
            for (int rr = 0; rr < 4; rr += 2) {
                float p0 = fexp2(s[4 * G + rr]);
                float p1 = fexp2(s[4 * G + rr + 1]);
                f32x2 pp; pp[0] = p0; pp[1] = p1;
                rsl += pp;
                pfrag[ci][e0 + rr] = (__bf16)p0;
                pfrag[ci][e0 + rr + 1] = (__bf16)p1;
            }
        }
    }
    __builtin_amdgcn_s_setprio(1);
#pragma unroll
    for (int c = 0; c < 4; c++) {
        int cc = (2 * c + h) ^ (col & 7);
        bf16x8 v0 = *(const bf16x8*)&vsb[(col * 8 + cc) * 8];
        bf16x8 v1 = *(const bf16x8*)&vsb[((32 + col) * 8 + cc) * 8];
        o0 = __builtin_amdgcn_mfma_f32_32x32x16_bf16(v0, pfrag[c], o0, 0, 0, 0);
        o1 = __builtin_amdgcn_mfma_f32_32x32x16_bf16(v1, pfrag[c], o1, 0, 0, 0);
    }
    __builtin_amdgcn_s_setprio(0);
}

// ---------------------------------------------------------------------------
// fused flash attention v13 (round-11 verified): compacted K/V, XCD-locality
// grid order (q-tile = slow dim). grid 512 x 512 threads.
// ---------------------------------------------------------------------------
__global__ __launch_bounds__(512, 4) void attn_kernel(const __bf16* __restrict__ qb,
                                                      const __bf16* __restrict__ kb,
                                                      const __bf16* __restrict__ vtb,
                                                      const int* __restrict__ cntg,
                                                      float* __restrict__ out) {
    __shared__ __align__(16) __bf16 ks[2][4096];
    __shared__ __align__(16) __bf16 vs[2][4096];

    int tid = threadIdx.x, wave = tid >> 6, lane = tid & 63;
    int col = lane & 31, h = lane >> 5;
    int bid = blockIdx.x;
    int qx = bid >> 6, r6 = bid & 63, hh = r6 >> 2, n = r6 & 3;
    int q0 = qx * 256;
    int cnt = cntg[n];
    int tiles = (cnt + 63) >> 6;
    int npad = (tiles << 6) - cnt;
    const __bf16* qg = qb + ((size_t)(n * HEADS + hh) * QLEN + q0 + wave * 32 + col) * HD;
    const __bf16* kg = kb + (size_t)(n * HEADS + hh) * KLEN * HD;
    const __bf16* vg = vtb + (size_t)(n * HEADS + hh) * HD * KLEN;

    // Q^T B-frags straight from global
    bf16x8 qfrag[4];
#pragma unroll
    for (int c = 0; c < 4; c++) qfrag[c] = *(const bf16x8*)&qg[c * 16 + h * 8];

    // DMA slot assignment (phi on k rows, XOR chunk swizzle); tid 0..511 spans
    // the full 64-row tile: R1 = tid>>3, one dma16 per array per tile.
    int R1 = tid >> 3, c1 = (tid & 7) ^ (R1 & 7);
    int g1 = (R1 & 0x33) | ((R1 & 4) << 1) | ((R1 & 8) >> 1);
    const __bf16* kgp1 = kg + g1 * HD + c1 * 8;
    const __bf16* vgp1 = vg + (size_t)R1 * KLEN + c1 * 8;

    // prologue: DMA tile 0 -> buf0
    dma16(kgp1, &ks[0][wave * 512]); dma16(vgp1, &vs[0][wave * 512]);
    kgp1 += 64 * HD; vgp1 += 64;
    __syncthreads();

    f32x16 o0 = {}, o1 = {};
    f32x2 rsl = {};

    for (int t = 0; t < tiles; t++) {
        int pc = t & 1, pn = pc ^ 1;
        if (t + 1 < tiles) {
            dma16(kgp1, &ks[pn][wave * 512]); dma16(vgp1, &vs[pn][wave * 512]);
            kgp1 += 64 * HD; vgp1 += 64;
        }
        SCHED_FENCE();
        attn_tile(ks[pc], vs[pc], qfrag, col, h, o0, o1, rsl);
        __syncthreads();
    }

    // epilogue: lane owns q-col q0+wave*32+col; subtract pad contribution
    float rs = rsl[0] + rsl[1];
    rs += __shfl_xor(rs, 32);
    rs -= (float)npad;
    float inv = 1.0f / rs;
    float* op = out + ((size_t)n * QLEN + q0 + wave * 32 + col) * EMBED + hh * HD;
#pragma unroll
    for (int G = 0; G < 4; G++) {
        float4 t0, t1;
        t0.x = o0[4 * G + 0] * inv; t0.y = o0[4 * G + 1] * inv;
        t0.z = o0[4 * G + 2] * inv; t0.w = o0[4 * G + 3] * inv;
        t1.x = o1[4 * G + 0] * inv; t1.y = o1[4 * G + 1] * inv;
        t1.z = o1[4 * G + 2] * inv; t1.w = o1[4 * G + 3] * inv;
        *(float4*)&op[8 * G + 4 * h] = t0;
        *(float4*)&op[32 + 8 * G + 4 * h] = t1;
    }
}

// ---------------------------------------------------------------------------
extern "C" void kernel_launch(void* const* d_in, const int* in_sizes, int n_in,
                              void* d_out, int out_size, void* d_ws, size_t ws_size,
                              hipStream_t stream) {
    const float* queries = (const float*)d_in[0];
    const float* keys    = (const float*)d_in[1];
    const float* values  = (const float*)d_in[2];
    const int*   mask    = (const int*)d_in[3];
    const float* Wq      = (const float*)d_in[4];
    const float* Wk      = (const float*)d_in[5];
    const float* Wv      = (const float*)d_in[6];
    float* out = (float*)d_out;

    const size_t MiB = 1048576;
    char* ws = (char*)d_ws;
    __bf16* qbf   = (__bf16*)(ws);             // 16 MiB  q   [N][H][Q][64] (pre-scaled)
    __bf16* kbf   = (__bf16*)(ws + 16 * MiB);  // 16 MiB  k   [N][H][K][64] compacted
    __bf16* vtbf  = (__bf16*)(ws + 32 * MiB);  // 16 MiB  vT  [N][H][64][K] compacted
    __bf16* wtq   = (__bf16*)(ws + 48 * MiB);  //  1 MiB
    __bf16* wtk   = (__bf16*)(ws + 49 * MiB);
    __bf16* wtv   = (__bf16*)(ws + 50 * MiB);
    __bf16* qin   = (__bf16*)(ws + 51 * MiB);  //  8 MiB
    __bf16* kin   = (__bf16*)(ws + 59 * MiB);  //  2 MiB
    __bf16* vin   = (__bf16*)(ws + 61 * MiB);  //  2 MiB
    int*    pidx  = (int*)(ws + 63 * MiB);               // 32 KiB dense->compact
    int*    cntg  = (int*)(ws + 63 * MiB + 65536);       // 16 B counts
    int*    cidx  = (int*)(ws + 63 * MiB + 131072);      // 32 KiB compact->dense
    int*    pst   = (int*)(ws + 63 * MiB + 196608);      // 272 B chunk p-offsets

    prep<<<4676, 256, 0, stream>>>(queries, keys, values, Wq, Wk, Wv, mask,
                                   qin, kin, vin, wtq, wtk, wtv,
                                   pidx, cntg, kbf, vtbf, cidx, pst);
    proj_all<<<768, 256, 0, stream>>>(qin, kin, vin, wtq, wtk, wtv,
                                      pidx, cidx, pst, qbf, kbf, vtbf);
    attn_kernel<<<512, 512, 0, stream>>>(qbf, kbf, vtbf, cntg, out);
}